// Round 7
// baseline (451.446 us; speedup 1.0000x reference)
//
#include <hip/hip_runtime.h>
#include <hip/hip_bf16.h>

#define NB 8
#define CIN 256
#define LL 4096
#define CQ 32
#define CV 256

typedef __attribute__((ext_vector_type(8))) short bf16x8;
typedef __attribute__((ext_vector_type(4))) float f32x4;
typedef __attribute__((ext_vector_type(16))) float f32x16;

__device__ __forceinline__ unsigned short f2bf(float f) {
    union { __hip_bfloat16 h; unsigned short u; } c;
    c.h = __float2bfloat16(f);
    return c.u;
}

// pack two f32 -> one u32 of 2 bf16 (lo = a, hi = b); RNE, matches f2bf
__device__ __forceinline__ unsigned cvtpk(float a, float b) {
    unsigned r;
    asm("v_cvt_pk_bf16_f32 %0, %1, %2" : "=v"(r) : "v"(a), "v"(b));
    return r;
}
// v_permlane32_swap_b32 D,S: D.hi-lanes <-> S.lo-lanes.
// After: x = [x.lo | y.lo], y = [x.hi | y.hi]  (m214-v22 construction)
__device__ __forceinline__ void pl32swap(unsigned &x, unsigned &y) {
    asm volatile("v_permlane32_swap_b32 %0, %1" : "+v"(x), "+v"(y));
}

// ---------------- K0: cast weights to bf16; Wq pre-scaled by log2(e) -----------
__global__ __launch_bounds__(256) void k_wcast(
    const float* __restrict__ Wq, const float* __restrict__ Wk,
    const float* __restrict__ Wv, const float* __restrict__ Wo,
    unsigned short* __restrict__ Wb, unsigned short* __restrict__ Wob)
{
    const float LOG2E = 1.4426950408889634f;
    const int row = blockIdx.x, t = threadIdx.x;
    if (row < 320) {
        float val;
        if (row < 32)      val = Wq[row * 256 + t] * LOG2E;
        else if (row < 64) val = Wk[(row - 32) * 256 + t];
        else               val = Wv[(row - 64) * 256 + t];
        Wb[row * 256 + t] = f2bf(val);
    } else {
        const int r2 = row - 320;
        Wob[r2 * 256 + t] = f2bf(Wo[r2 * 256 + t]);
    }
}

// ---------------- K1: fused QKV projection, MFMA bf16, 8 waves -----------------
__global__ __launch_bounds__(512) void k_qkv3(
    const float* __restrict__ x, const unsigned short* __restrict__ Wb,
    unsigned short* __restrict__ qkt, unsigned short* __restrict__ v)
{
    __shared__ unsigned short xlds[64][264];
    __shared__ unsigned short tr[64][72];
    const int n = blockIdx.y, l0 = blockIdx.x * 64, t = threadIdx.x;
    const int w = t >> 6, lane = t & 63, lid = lane & 15, quad = lane >> 4;

    #pragma unroll
    for (int part = 0; part < 4; part++) {
        const int cbase = part * 64 + w * 8;
        float tmp[8];
        #pragma unroll
        for (int cc = 0; cc < 8; cc++)
            tmp[cc] = x[((size_t)n * CIN + cbase + cc) * LL + l0 + lane];
        bf16x8 s;
        #pragma unroll
        for (int cc = 0; cc < 8; cc++) s[cc] = (short)f2bf(tmp[cc]);
        *(bf16x8*)&xlds[lane][cbase] = s;
    }
    __syncthreads();

    const f32x4 fzero = {0.f, 0.f, 0.f, 0.f};
    f32x4 acc[3][4];
    #pragma unroll
    for (int mt = 0; mt < 3; mt++)
        #pragma unroll
        for (int nt = 0; nt < 4; nt++) acc[mt][nt] = fzero;

    for (int k0 = 0; k0 < 256; k0 += 32) {
        bf16x8 bx[4];
        #pragma unroll
        for (int nt = 0; nt < 4; nt++)
            bx[nt] = *(const bf16x8*)&xlds[nt * 16 + lid][k0 + quad * 8];
        #pragma unroll
        for (int vt = 0; vt < 2; vt++) {
            const bf16x8 wa = *(const bf16x8*)&Wb[(64 + w * 32 + vt * 16 + lid) * 256 + k0 + quad * 8];
            #pragma unroll
            for (int nt = 0; nt < 4; nt++)
                acc[vt][nt] = __builtin_amdgcn_mfma_f32_16x16x32_bf16(wa, bx[nt], acc[vt][nt], 0, 0, 0);
        }
        if (w < 4) {
            const bf16x8 wa = *(const bf16x8*)&Wb[(w * 16 + lid) * 256 + k0 + quad * 8];
            #pragma unroll
            for (int nt = 0; nt < 4; nt++)
                acc[2][nt] = __builtin_amdgcn_mfma_f32_16x16x32_bf16(wa, bx[nt], acc[2][nt], 0, 0, 0);
        }
    }
    #pragma unroll
    for (int vt = 0; vt < 2; vt++)
        #pragma unroll
        for (int nt = 0; nt < 4; nt++)
            #pragma unroll
            for (int reg = 0; reg < 4; reg++) {
                const int vr = w * 32 + vt * 16 + quad * 4 + reg;
                v[((size_t)n * CV + vr) * LL + l0 + nt * 16 + lid] = f2bf(acc[vt][nt][reg]);
            }
    if (w < 4) {
        #pragma unroll
        for (int nt = 0; nt < 4; nt++)
            #pragma unroll
            for (int reg = 0; reg < 4; reg++)
                tr[nt * 16 + lid][w * 16 + quad * 4 + reg] = f2bf(acc[2][nt][reg]);
    }
    __syncthreads();
    {
        const int l = t >> 3, c = (t & 7) * 8;
        *(uint4*)&qkt[((size_t)n * LL + l0 + l) * 64 + c] = *(const uint4*)&tr[l][c];
    }
}

// ---------------- K2: lns[i] = -log2( sum_j 2^(e2_ij) ), 8 waves ---------------
__global__ __launch_bounds__(512) void k_rowsum3(
    const unsigned short* __restrict__ qkt, float* __restrict__ lns)
{
    __shared__ float red[64];
    const int n = blockIdx.y, i0 = blockIdx.x * 64, t = threadIdx.x;
    const int w = t >> 6, lid = t & 15, quad = (t & 63) >> 4;
    if (t < 64) red[t] = 0.f;
    __syncthreads();

    bf16x8 aq[4];
    #pragma unroll
    for (int mt = 0; mt < 4; mt++)
        aq[mt] = *(const bf16x8*)&qkt[((size_t)n * LL + i0 + mt * 16 + lid) * 64 + quad * 8];

    const f32x4 fzero = {0.f, 0.f, 0.f, 0.f};
    float sums[4][4];
    #pragma unroll
    for (int mt = 0; mt < 4; mt++)
        #pragma unroll
        for (int reg = 0; reg < 4; reg++) sums[mt][reg] = 0.f;

    for (int jt = 0; jt < 8; jt++) {
        const int j0 = jt * 512 + w * 64;
        bf16x8 bk[4];
        #pragma unroll
        for (int nt = 0; nt < 4; nt++)
            bk[nt] = *(const bf16x8*)&qkt[((size_t)n * LL + j0 + nt * 16 + lid) * 64 + 32 + quad * 8];
        #pragma unroll
        for (int mt = 0; mt < 4; mt++)
            #pragma unroll
            for (int nt = 0; nt < 4; nt++) {
                f32x4 e = __builtin_amdgcn_mfma_f32_16x16x32_bf16(aq[mt], bk[nt], fzero, 0, 0, 0);
                sums[mt][0] += __builtin_amdgcn_exp2f(e[0]);
                sums[mt][1] += __builtin_amdgcn_exp2f(e[1]);
                sums[mt][2] += __builtin_amdgcn_exp2f(e[2]);
                sums[mt][3] += __builtin_amdgcn_exp2f(e[3]);
            }
    }
    #pragma unroll
    for (int mt = 0; mt < 4; mt++)
        #pragma unroll
        for (int reg = 0; reg < 4; reg++) {
            float s = sums[mt][reg];
            s += __shfl_xor(s, 1); s += __shfl_xor(s, 2);
            s += __shfl_xor(s, 4); s += __shfl_xor(s, 8);
            if (lid == 0) atomicAdd(&red[mt * 16 + quad * 4 + reg], s);
        }
    __syncthreads();
    if (t < 64) lns[(size_t)n * LL + i0 + t] = -__builtin_log2f(red[t]);
}

// ---------------- K3: register-resident P attention + out-proj -----------------
// R7 STRUCTURAL (six rounds prove the P->LDS->barrier round-trip IS the cost):
// 32x32x16 MFMA path. E = mfma(A=Q_i, B=K_j) -> lane holds P[i][j] for j=lane&31
// (16 i-values in C regs). That IS the A-operand axis of O^T = P^T V^T: A-row=j,
// k=i. Redistribute i-halves with 8 cvt_pk + 4 permlane32_swap per P-tile
// (m214-v22). => NO LDS, NO barriers in the main loop; each wave independent.
//   wave = (j-tile 32, v-half 128), iterates all i in 32-chunks.
//   2048 waves = 256 blocks x 8 (512 thr); n = bid&7 -> per-XCD V locality.
//   bare s_barrier every 4 chunks phase-locks the 8 waves for L1 V-reuse.
// C layout (m74/m101): row=(reg&3)+8*(reg>>2)+4*(lane>>5), col=lane&31.
__global__ __launch_bounds__(512, 2) void k_attn15(
    const unsigned short* __restrict__ qkt, const unsigned short* __restrict__ v,
    const float* __restrict__ lns, const unsigned short* __restrict__ Wob,
    const float* __restrict__ gp, float* __restrict__ out)
{
    __shared__ unsigned short olds[128][264];   // 67584 B, epilogue only

    const int bid = blockIdx.x;
    const int n = bid & 7, jblk = bid >> 3;     // jblk 0..31
    const int t = threadIdx.x;
    const int w = t >> 6, lane = t & 63, l31 = lane & 31, hi = lane >> 5;
    const int jt = w >> 1, vh = w & 1;
    const int j0w = jblk * 128 + jt * 32;
    const int v0w = vh * 128;

    // K B-frags (i-invariant): col j = j0w + l31, c-slices [0,16),[16,32)
    const bf16x8 bk0 = *(const bf16x8*)&qkt[((size_t)n * LL + j0w + l31) * 64 + 32 + hi * 8];
    const bf16x8 bk1 = *(const bf16x8*)&qkt[((size_t)n * LL + j0w + l31) * 64 + 48 + hi * 8];

    const unsigned short* qbase = qkt + (size_t)n * LL * 64;
    const float* lbase = lns + (size_t)n * LL;
    const unsigned short* vbase = v + ((size_t)n * CV + v0w + l31) * LL;

    f32x16 oacc0, oacc1, oacc2, oacc3;          // vb 0..3 (v = v0w+vb*32+l31)
    #pragma unroll
    for (int r = 0; r < 16; r++) { oacc0[r] = 0.f; oacc1[r] = 0.f; oacc2[r] = 0.f; oacc3[r] = 0.f; }

    for (int ic = 0; ic < 128; ic++) {
        const int i0 = ic * 32;
        // Q A-frags: row i = i0+l31, c-slices
        const bf16x8 aq0 = *(const bf16x8*)&qbase[((size_t)(i0 + l31)) * 64 + hi * 8];
        const bf16x8 aq1 = *(const bf16x8*)&qbase[((size_t)(i0 + l31)) * 64 + 16 + hi * 8];
        // lns C-in: e[g*4+r] = lns[i0 + r + 8g + 4hi]
        f32x16 e;
        {
            const f32x4 g0 = *(const f32x4*)&lbase[i0 + 0 + hi * 4];
            const f32x4 g1 = *(const f32x4*)&lbase[i0 + 8 + hi * 4];
            const f32x4 g2 = *(const f32x4*)&lbase[i0 + 16 + hi * 4];
            const f32x4 g3 = *(const f32x4*)&lbase[i0 + 24 + hi * 4];
            e[0] = g0[0];  e[1] = g0[1];  e[2] = g0[2];  e[3] = g0[3];
            e[4] = g1[0];  e[5] = g1[1];  e[6] = g1[2];  e[7] = g1[3];
            e[8] = g2[0];  e[9] = g2[1];  e[10] = g2[2]; e[11] = g2[3];
            e[12] = g3[0]; e[13] = g3[1]; e[14] = g3[2]; e[15] = g3[3];
        }
        // V B-frags: col v = v0w+vb*32+l31, k-slices i0+s*16+hi*8
        const bf16x8 bv00 = *(const bf16x8*)(vbase + (size_t)0 * 32 * LL + i0 + hi * 8);
        const bf16x8 bv01 = *(const bf16x8*)(vbase + (size_t)0 * 32 * LL + i0 + 16 + hi * 8);
        const bf16x8 bv10 = *(const bf16x8*)(vbase + (size_t)1 * 32 * LL + i0 + hi * 8);
        const bf16x8 bv11 = *(const bf16x8*)(vbase + (size_t)1 * 32 * LL + i0 + 16 + hi * 8);
        const bf16x8 bv20 = *(const bf16x8*)(vbase + (size_t)2 * 32 * LL + i0 + hi * 8);
        const bf16x8 bv21 = *(const bf16x8*)(vbase + (size_t)2 * 32 * LL + i0 + 16 + hi * 8);
        const bf16x8 bv30 = *(const bf16x8*)(vbase + (size_t)3 * 32 * LL + i0 + hi * 8);
        const bf16x8 bv31 = *(const bf16x8*)(vbase + (size_t)3 * 32 * LL + i0 + 16 + hi * 8);
        // E: e = Q.K + lns  (log2-domain; Wq pre-scaled)
        e = __builtin_amdgcn_mfma_f32_32x32x16_bf16(aq0, bk0, e, 0, 0, 0);
        e = __builtin_amdgcn_mfma_f32_32x32x16_bf16(aq1, bk1, e, 0, 0, 0);
        // P = 2^e; pack to bf16 and redistribute i-halves across lane-halves.
        // s=0 (i_local 0..15): regs g0,g1; s=1 (16..31): g2,g3.
        unsigned a0 = cvtpk(__builtin_amdgcn_exp2f(e[0]), __builtin_amdgcn_exp2f(e[1]));
        unsigned b0 = cvtpk(__builtin_amdgcn_exp2f(e[4]), __builtin_amdgcn_exp2f(e[5]));
        pl32swap(a0, b0);   // a0 = pa0.e01, b0 = pa0.e45
        unsigned a1 = cvtpk(__builtin_amdgcn_exp2f(e[2]), __builtin_amdgcn_exp2f(e[3]));
        unsigned b1 = cvtpk(__builtin_amdgcn_exp2f(e[6]), __builtin_amdgcn_exp2f(e[7]));
        pl32swap(a1, b1);   // a1 = pa0.e23, b1 = pa0.e67
        unsigned a2 = cvtpk(__builtin_amdgcn_exp2f(e[8]), __builtin_amdgcn_exp2f(e[9]));
        unsigned b2 = cvtpk(__builtin_amdgcn_exp2f(e[12]), __builtin_amdgcn_exp2f(e[13]));
        pl32swap(a2, b2);
        unsigned a3 = cvtpk(__builtin_amdgcn_exp2f(e[10]), __builtin_amdgcn_exp2f(e[11]));
        unsigned b3 = cvtpk(__builtin_amdgcn_exp2f(e[14]), __builtin_amdgcn_exp2f(e[15]));
        pl32swap(a3, b3);
        union { unsigned u[4]; bf16x8 v8; } pa0c, pa1c;
        pa0c.u[0] = a0; pa0c.u[1] = a1; pa0c.u[2] = b0; pa0c.u[3] = b1;
        pa1c.u[0] = a2; pa1c.u[1] = a3; pa1c.u[2] = b2; pa1c.u[3] = b3;
        const bf16x8 pa0 = pa0c.v8, pa1 = pa1c.v8;
        // O^T accumulate: C[row=j][col=v]
        oacc0 = __builtin_amdgcn_mfma_f32_32x32x16_bf16(pa0, bv00, oacc0, 0, 0, 0);
        oacc0 = __builtin_amdgcn_mfma_f32_32x32x16_bf16(pa1, bv01, oacc0, 0, 0, 0);
        oacc1 = __builtin_amdgcn_mfma_f32_32x32x16_bf16(pa0, bv10, oacc1, 0, 0, 0);
        oacc1 = __builtin_amdgcn_mfma_f32_32x32x16_bf16(pa1, bv11, oacc1, 0, 0, 0);
        oacc2 = __builtin_amdgcn_mfma_f32_32x32x16_bf16(pa0, bv20, oacc2, 0, 0, 0);
        oacc2 = __builtin_amdgcn_mfma_f32_32x32x16_bf16(pa1, bv21, oacc2, 0, 0, 0);
        oacc3 = __builtin_amdgcn_mfma_f32_32x32x16_bf16(pa0, bv30, oacc3, 0, 0, 0);
        oacc3 = __builtin_amdgcn_mfma_f32_32x32x16_bf16(pa1, bv31, oacc3, 0, 0, 0);
        // phase re-lock (pure rendezvous, no waitcnt) for L1 V-reuse
        if ((ic & 3) == 3) __builtin_amdgcn_s_barrier();
    }

    // ---- epilogue: stage O^T -> olds[jloc][v] (bf16), then block out-proj ----
    #pragma unroll
    for (int r = 0; r < 16; r++) {
        const int jl = jt * 32 + (r & 3) + 8 * (r >> 2) + 4 * hi;
        olds[jl][v0w + 0 * 32 + l31] = f2bf(oacc0[r]);
        olds[jl][v0w + 1 * 32 + l31] = f2bf(oacc1[r]);
        olds[jl][v0w + 2 * 32 + l31] = f2bf(oacc2[r]);
        olds[jl][v0w + 3 * 32 + l31] = f2bf(oacc3[r]);
    }
    __syncthreads();
    // out-proj: wave w -> out rows [w*32, w*32+32), block j-span 128
    const float g = *gp;
    for (int jt2 = 0; jt2 < 4; jt2++) {
        f32x16 oc;
        #pragma unroll
        for (int r = 0; r < 16; r++) oc[r] = 0.f;
        #pragma unroll
        for (int kk = 0; kk < 16; kk++) {
            const bf16x8 wa = *(const bf16x8*)&Wob[(w * 32 + l31) * 256 + kk * 16 + hi * 8];
            const bf16x8 ob = *(const bf16x8*)&olds[jt2 * 32 + l31][kk * 16 + hi * 8];
            oc = __builtin_amdgcn_mfma_f32_32x32x16_bf16(wa, ob, oc, 0, 0, 0);
        }
        #pragma unroll
        for (int r = 0; r < 16; r++) {
            const int rr = w * 32 + (r & 3) + 8 * (r >> 2) + 4 * hi;
            out[((size_t)n * CIN + rr) * LL + jblk * 128 + jt2 * 32 + l31] = g * oc[r];
        }
    }
}

extern "C" void kernel_launch(void* const* d_in, const int* in_sizes, int n_in,
                              void* d_out, int out_size, void* d_ws, size_t ws_size,
                              hipStream_t stream) {
    const float* x     = (const float*)d_in[0];
    const float* Wq    = (const float*)d_in[1];
    const float* Wk    = (const float*)d_in[2];
    const float* Wv    = (const float*)d_in[3];
    const float* Wo    = (const float*)d_in[4];
    const float* gamma = (const float*)d_in[5];

    unsigned short* qkt = (unsigned short*)d_ws;              // 4 MB
    unsigned short* v   = qkt + (size_t)NB * LL * 64;         // 16 MB
    unsigned short* Wb  = v + (size_t)NB * CV * LL;           // 160 KB
    unsigned short* Wob = Wb + 320 * 256;                     // 128 KB
    float* lns          = (float*)(Wob + 256 * 256);          // 128 KB
    float* out = (float*)d_out;

    k_wcast  <<<dim3(576),   256, 0, stream>>>(Wq, Wk, Wv, Wo, Wb, Wob);
    k_qkv3   <<<dim3(64, 8), 512, 0, stream>>>(x, Wb, qkt, v);
    k_rowsum3<<<dim3(64, 8), 512, 0, stream>>>(qkt, lns);
    k_attn15 <<<dim3(256),   512, 0, stream>>>(qkt, v, lns, Wob, gamma, out);
}